// Round 1
// baseline (312.549 us; speedup 1.0000x reference)
//
#include <hip/hip_runtime.h>

#define DEV __device__ __forceinline__

typedef __attribute__((ext_vector_type(8))) short short8;
typedef __attribute__((ext_vector_type(4))) float f32x4;
typedef __bf16 bf16x8 __attribute__((ext_vector_type(8)));
typedef unsigned int u32;
typedef unsigned short u16;

constexpr int Bb = 2, Ss = 2048, Dd = 1024, Hh = 16, DKc = 64;
constexpr int Kk = 1024;   // inner dim of all projection GEMMs

// ---- fp32 <-> bf16 (RNE), no hip_bf16 dependency ----
DEV u16 f2bf(float f) {
  u32 u = __builtin_bit_cast(u32, f);
  u32 r = (u + 0x7fffu + ((u >> 16) & 1u)) >> 16;
  return (u16)r;
}

DEV f32x4 mfma16(short8 a, short8 b, f32x4 c) {
  return __builtin_amdgcn_mfma_f32_16x16x32_bf16(
      __builtin_bit_cast(bf16x8, a), __builtin_bit_cast(bf16x8, b), c, 0, 0, 0);
}

DEV void gload_lds16(const u16* g, u16* lds) {
  __builtin_amdgcn_global_load_lds(
      (const __attribute__((address_space(1))) u32*)g,
      (__attribute__((address_space(3))) u32*)lds, 16, 0, 0);
}

// ---------------- fp32 -> bf16 conversion (7 tensors in one launch) ----------------
struct CvtArgs {
  const float* in[7];
  u16* out[7];
  int n[7];
};

__global__ __launch_bounds__(256) void cvt_all(CvtArgs a) {
  int z = blockIdx.z;
  int i = (blockIdx.x * 256 + threadIdx.x) * 4;
  if (i >= a.n[z]) return;
  float4 v = *reinterpret_cast<const float4*>(a.in[z] + i);
  ushort4 o;
  o.x = f2bf(v.x); o.y = f2bf(v.y); o.z = f2bf(v.z); o.w = f2bf(v.w);
  *reinterpret_cast<ushort4*>(a.out[z] + i) = o;
}

// ---------------- shared 128x128xK GEMM core (A, Bt both row-major [rows][K] bf16) ----
DEV void gemm_core_128(const u16* __restrict__ A, const u16* __restrict__ Bt,
                       u16* smA, u16* smB, f32x4 acc[4][4], int gm0, int gn0) {
  const int tid = threadIdx.x;
  const int w = tid >> 6, l = tid & 63;
  const int g = l >> 4, r = l & 15;
  const int wm = w >> 1, wn = w & 1;
  const int srow = l >> 2, scol = (l & 3) * 8;  // staging: 16 rows x 32 cols per 1KB chunk

  auto stage = [&](int kt) {
    int kb = kt * 32;
#pragma unroll
    for (int cc = 0; cc < 2; ++cc) {
      int c = w + cc * 4;                      // 8 chunks of 16 rows, 2 per wave
      gload_lds16(A + (size_t)(gm0 + c * 16 + srow) * Kk + kb + scol, smA + c * 512);
      gload_lds16(Bt + (size_t)(gn0 + c * 16 + srow) * Kk + kb + scol, smB + c * 512);
    }
  };

  stage(0);
  for (int kt = 0; kt < Kk / 32; ++kt) {
    __syncthreads();          // staging of tile kt complete (vmcnt drained)
    short8 af[4], bf_[4];
#pragma unroll
    for (int t = 0; t < 4; ++t) {
      af[t]  = *reinterpret_cast<const short8*>(smA + ((wm * 64 + t * 16 + r) * 32 + g * 8));
      bf_[t] = *reinterpret_cast<const short8*>(smB + ((wn * 64 + t * 16 + r) * 32 + g * 8));
    }
#pragma unroll
    for (int mt = 0; mt < 4; ++mt)
#pragma unroll
      for (int nt = 0; nt < 4; ++nt)
        acc[mt][nt] = mfma16(af[mt], bf_[nt], acc[mt][nt]);
    __syncthreads();          // all waves done reading before overwrite
    if (kt + 1 < Kk / 32) stage(kt + 1);
  }
}

// ---------------- QKV projection: z=0 Q, z=1 K -> (B,H,S,DK); z=2 V -> (B,H,DK,S) ----
__global__ __launch_bounds__(256) void proj_qkv(
    const u16* __restrict__ xq, const u16* __restrict__ xk, const u16* __restrict__ xv,
    const u16* __restrict__ Wq, const u16* __restrict__ Wk, const u16* __restrict__ Wv,
    const float* __restrict__ bq, const float* __restrict__ bk, const float* __restrict__ bv,
    u16* __restrict__ Qh, u16* __restrict__ Kh, u16* __restrict__ Vt) {
  __shared__ u16 smA[128 * 32], smB[128 * 32];
  const int z = blockIdx.z;
  const u16* A = z == 0 ? xq : (z == 1 ? xk : xv);
  const u16* W = z == 0 ? Wq : (z == 1 ? Wk : Wv);
  const float* bias = z == 0 ? bq : (z == 1 ? bk : bv);
  u16* out = z == 0 ? Qh : (z == 1 ? Kh : Vt);
  const int gm0 = blockIdx.y * 128, gn0 = blockIdx.x * 128;
  f32x4 acc[4][4] = {};
  gemm_core_128(A, W, smA, smB, acc, gm0, gn0);

  const int tid = threadIdx.x;
  const int w = tid >> 6, l = tid & 63, g = l >> 4, r = l & 15;
  const int wm = w >> 1, wn = w & 1;
#pragma unroll
  for (int mt = 0; mt < 4; ++mt) {
#pragma unroll
    for (int nt = 0; nt < 4; ++nt) {
      int ncol = gn0 + wn * 64 + nt * 16 + r;
      int h = ncol >> 6, dk = ncol & 63;
      float bb = bias[ncol];
#pragma unroll
      for (int i = 0; i < 4; ++i) {
        int mrow = gm0 + wm * 64 + mt * 16 + g * 4 + i;
        int b = mrow >> 11, s = mrow & 2047;
        float v = acc[mt][nt][i] + bb;
        if (z < 2)
          out[(((size_t)b * Hh + h) * Ss + s) * DKc + dk] = f2bf(v);
        else
          out[(((size_t)b * Hh + h) * DKc + dk) * Ss + s] = f2bf(v);
      }
    }
  }
}

// ---------------- causal flash attention: 4 waves x 16 q-rows, barrier-free ----------
__global__ __launch_bounds__(256) void attn(
    const u16* __restrict__ Qh, const u16* __restrict__ Kh,
    const u16* __restrict__ Vt, u16* __restrict__ Ob) {
  __shared__ u16 Pt[4][16][40];   // per-wave P-transpose tile, padded rows (16B-aligned reads)
  const int bh = blockIdx.y;
  const int bidx = bh >> 4, h = bh & 15;
  const int tid = threadIdx.x, w = tid >> 6, l = tid & 63;
  const int g = l >> 4, r = l & 15;
  const int q0 = blockIdx.x * 64 + w * 16;

  const u16* Qb = Qh + (size_t)bh * Ss * DKc;
  const u16* Kb = Kh + (size_t)bh * Ss * DKc;
  const u16* Vb = Vt + (size_t)bh * DKc * Ss;

  short8 qf[2];
  qf[0] = *reinterpret_cast<const short8*>(Qb + (size_t)(q0 + r) * DKc + g * 8);
  qf[1] = *reinterpret_cast<const short8*>(Qb + (size_t)(q0 + r) * DKc + 32 + g * 8);

  f32x4 o[4] = {};
  float m_i[4], l_i[4];
#pragma unroll
  for (int i = 0; i < 4; ++i) { m_i[i] = -3e38f; l_i[i] = 0.f; }

  const int ntile = (q0 + 15) / 32 + 1;   // causal: last tile touching q0+15
  for (int kt = 0; kt < ntile; ++kt) {
    const int kb = kt * 32;
    f32x4 sa = {}, sb = {};
    // K fragments direct from global: rows kb+r / kb+16+r, d-chunks 0,32
    short8 k00 = *reinterpret_cast<const short8*>(Kb + (size_t)(kb + r) * DKc + g * 8);
    short8 k01 = *reinterpret_cast<const short8*>(Kb + (size_t)(kb + r) * DKc + 32 + g * 8);
    short8 k10 = *reinterpret_cast<const short8*>(Kb + (size_t)(kb + 16 + r) * DKc + g * 8);
    short8 k11 = *reinterpret_cast<const short8*>(Kb + (size_t)(kb + 16 + r) * DKc + 32 + g * 8);
    sa = mfma16(qf[0], k00, sa); sa = mfma16(qf[1], k01, sa);
    sb = mfma16(qf[0], k10, sb); sb = mfma16(qf[1], k11, sb);

#pragma unroll
    for (int i = 0; i < 4; ++i) {
      const int q = q0 + g * 4 + i;
      float a = sa[i] * 0.125f, b = sb[i] * 0.125f;
      if (kb + r > q)       a = -1e30f;   // causal mask
      if (kb + 16 + r > q)  b = -1e30f;
      float t = fmaxf(a, b);
      t = fmaxf(t, __shfl_xor(t, 1)); t = fmaxf(t, __shfl_xor(t, 2));
      t = fmaxf(t, __shfl_xor(t, 4)); t = fmaxf(t, __shfl_xor(t, 8));
      float mn = fmaxf(m_i[i], t);
      float f = __expf(m_i[i] - mn);
      m_i[i] = mn;
      float pa = __expf(a - mn), pb = __expf(b - mn);
      float rs = pa + pb;
      rs += __shfl_xor(rs, 1); rs += __shfl_xor(rs, 2);
      rs += __shfl_xor(rs, 4); rs += __shfl_xor(rs, 8);
      l_i[i] = l_i[i] * f + rs;
#pragma unroll
      for (int dt = 0; dt < 4; ++dt) o[dt][i] *= f;
      Pt[w][g * 4 + i][r]      = f2bf(pa);
      Pt[w][g * 4 + i][16 + r] = f2bf(pb);
    }

    // PV: A-frag = P[r][g*8..+7] from LDS (wave-private; lgkmcnt ordering by compiler)
    short8 pf = *reinterpret_cast<const short8*>(&Pt[w][r][g * 8]);
#pragma unroll
    for (int dt = 0; dt < 4; ++dt) {
      short8 vf = *reinterpret_cast<const short8*>(Vb + (size_t)(dt * 16 + r) * Ss + kb + g * 8);
      o[dt] = mfma16(pf, vf, o[dt]);
    }
  }

#pragma unroll
  for (int i = 0; i < 4; ++i) {
    float inv = 1.f / l_i[i];
    int s = q0 + g * 4 + i;
#pragma unroll
    for (int dt = 0; dt < 4; ++dt)
      Ob[((size_t)bidx * Ss + s) * Dd + h * DKc + dt * 16 + r] = f2bf(o[dt][i] * inv);
  }
}

// ---------------- output projection: bf16 A,W -> fp32 out + bias ----------------
__global__ __launch_bounds__(256) void gemm_out(
    const u16* __restrict__ Ob, const u16* __restrict__ Wo,
    const float* __restrict__ bo, float* __restrict__ out) {
  __shared__ u16 smA[128 * 32], smB[128 * 32];
  const int gm0 = blockIdx.y * 128, gn0 = blockIdx.x * 128;
  f32x4 acc[4][4] = {};
  gemm_core_128(Ob, Wo, smA, smB, acc, gm0, gn0);

  const int tid = threadIdx.x;
  const int w = tid >> 6, l = tid & 63, g = l >> 4, r = l & 15;
  const int wm = w >> 1, wn = w & 1;
#pragma unroll
  for (int mt = 0; mt < 4; ++mt) {
#pragma unroll
    for (int nt = 0; nt < 4; ++nt) {
      int ncol = gn0 + wn * 64 + nt * 16 + r;
      float bb = bo[ncol];
#pragma unroll
      for (int i = 0; i < 4; ++i) {
        int mrow = gm0 + wm * 64 + mt * 16 + g * 4 + i;
        out[(size_t)mrow * Dd + ncol] = acc[mt][nt][i] + bb;
      }
    }
  }
}

extern "C" void kernel_launch(void* const* d_in, const int* in_sizes, int n_in,
                              void* d_out, int out_size, void* d_ws, size_t ws_size,
                              hipStream_t stream) {
  const float* q    = (const float*)d_in[0];
  const float* k    = (const float*)d_in[1];
  const float* v    = (const float*)d_in[2];
  // d_in[3] = mask (causal tril) — handled analytically
  const float* wq_w = (const float*)d_in[4];
  const float* wq_b = (const float*)d_in[5];
  const float* wk_w = (const float*)d_in[6];
  const float* wk_b = (const float*)d_in[7];
  const float* wv_w = (const float*)d_in[8];
  const float* wv_b = (const float*)d_in[9];
  const float* wo_w = (const float*)d_in[10];
  const float* wo_b = (const float*)d_in[11];

  char* ws = (char*)d_ws;
  u16* xq  = (u16*)(ws + 0);
  u16* xk  = (u16*)(ws + 8388608);
  u16* xv  = (u16*)(ws + 16777216);
  u16* Wqb = (u16*)(ws + 25165824);
  u16* Wkb = (u16*)(ws + 27262976);
  u16* Wvb = (u16*)(ws + 29360128);
  u16* Wob = (u16*)(ws + 31457280);
  u16* Qh  = (u16*)(ws + 33554432);
  u16* Kh  = (u16*)(ws + 41943040);
  u16* Vt  = (u16*)(ws + 50331648);
  u16* Ob  = (u16*)(ws + 0);        // alias xq: dead after projections

  CvtArgs ca;
  ca.in[0] = q;    ca.out[0] = xq;  ca.n[0] = 4194304;
  ca.in[1] = k;    ca.out[1] = xk;  ca.n[1] = 4194304;
  ca.in[2] = v;    ca.out[2] = xv;  ca.n[2] = 4194304;
  ca.in[3] = wq_w; ca.out[3] = Wqb; ca.n[3] = 1048576;
  ca.in[4] = wk_w; ca.out[4] = Wkb; ca.n[4] = 1048576;
  ca.in[5] = wv_w; ca.out[5] = Wvb; ca.n[5] = 1048576;
  ca.in[6] = wo_w; ca.out[6] = Wob; ca.n[6] = 1048576;

  cvt_all<<<dim3(4096, 1, 7), 256, 0, stream>>>(ca);
  proj_qkv<<<dim3(8, 32, 3), 256, 0, stream>>>(xq, xk, xv, Wqb, Wkb, Wvb,
                                               wq_b, wk_b, wv_b, Qh, Kh, Vt);
  attn<<<dim3(32, 32), 256, 0, stream>>>(Qh, Kh, Vt, Ob);
  gemm_out<<<dim3(8, 32), 256, 0, stream>>>(Ob, Wob, wo_b, (float*)d_out);
}

// Round 2
// 169.838 us; speedup vs baseline: 1.8403x; 1.8403x over previous
//
#include <hip/hip_runtime.h>

#define DEV __device__ __forceinline__

typedef __attribute__((ext_vector_type(8))) short short8;
typedef __attribute__((ext_vector_type(4))) float f32x4;
typedef __bf16 bf16x8 __attribute__((ext_vector_type(8)));
typedef unsigned int u32;
typedef unsigned short u16;

constexpr int Bb = 2, Ss = 2048, Dd = 1024, Hh = 16, DKc = 64;
constexpr int Kk = 1024;   // inner dim of all projection GEMMs

// ---- fp32 <-> bf16 (RNE), no hip_bf16 dependency ----
DEV u16 f2bf(float f) {
  u32 u = __builtin_bit_cast(u32, f);
  u32 r = (u + 0x7fffu + ((u >> 16) & 1u)) >> 16;
  return (u16)r;
}

DEV f32x4 mfma16(short8 a, short8 b, f32x4 c) {
  return __builtin_amdgcn_mfma_f32_16x16x32_bf16(
      __builtin_bit_cast(bf16x8, a), __builtin_bit_cast(bf16x8, b), c, 0, 0, 0);
}

DEV void gload_lds16(const u16* g, u16* lds) {
  __builtin_amdgcn_global_load_lds(
      (const __attribute__((address_space(1))) u32*)g,
      (__attribute__((address_space(3))) u32*)lds, 16, 0, 0);
}

// ---------------- fp32 -> bf16 conversion (7 tensors in one launch) ----------------
struct CvtArgs {
  const float* in[7];
  u16* out[7];
  int n[7];
};

__global__ __launch_bounds__(256) void cvt_all(CvtArgs a) {
  int z = blockIdx.z;
  int i = (blockIdx.x * 256 + threadIdx.x) * 4;
  if (i >= a.n[z]) return;
  float4 v = *reinterpret_cast<const float4*>(a.in[z] + i);
  ushort4 o;
  o.x = f2bf(v.x); o.y = f2bf(v.y); o.z = f2bf(v.z); o.w = f2bf(v.w);
  *reinterpret_cast<ushort4*>(a.out[z] + i) = o;
}

// ---------------- shared 128x128xK GEMM core (A, Bt both row-major [rows][K] bf16) ----
DEV void gemm_core_128(const u16* __restrict__ A, const u16* __restrict__ Bt,
                       u16* smA, u16* smB, f32x4 acc[4][4], int gm0, int gn0) {
  const int tid = threadIdx.x;
  const int w = tid >> 6, l = tid & 63;
  const int g = l >> 4, r = l & 15;
  const int wm = w >> 1, wn = w & 1;
  const int srow = l >> 2, scol = (l & 3) * 8;  // staging: 16 rows x 32 cols per 1KB chunk

  auto stage = [&](int kt) {
    int kb = kt * 32;
#pragma unroll
    for (int cc = 0; cc < 2; ++cc) {
      int c = w + cc * 4;                      // 8 chunks of 16 rows, 2 per wave
      gload_lds16(A + (size_t)(gm0 + c * 16 + srow) * Kk + kb + scol, smA + c * 512);
      gload_lds16(Bt + (size_t)(gn0 + c * 16 + srow) * Kk + kb + scol, smB + c * 512);
    }
  };

  stage(0);
  for (int kt = 0; kt < Kk / 32; ++kt) {
    __syncthreads();          // staging of tile kt complete (vmcnt drained)
    short8 af[4], bf_[4];
#pragma unroll
    for (int t = 0; t < 4; ++t) {
      af[t]  = *reinterpret_cast<const short8*>(smA + ((wm * 64 + t * 16 + r) * 32 + g * 8));
      bf_[t] = *reinterpret_cast<const short8*>(smB + ((wn * 64 + t * 16 + r) * 32 + g * 8));
    }
#pragma unroll
    for (int mt = 0; mt < 4; ++mt)
#pragma unroll
      for (int nt = 0; nt < 4; ++nt)
        acc[mt][nt] = mfma16(af[mt], bf_[nt], acc[mt][nt]);
    __syncthreads();          // all waves done reading before overwrite
    if (kt + 1 < Kk / 32) stage(kt + 1);
  }
}

// ---------------- QKV projection: z=0 Q, z=1 K -> (B,H,S,DK); z=2 V -> (B,H,DK,S) ----
__global__ __launch_bounds__(256) void proj_qkv(
    const u16* __restrict__ xq, const u16* __restrict__ xk, const u16* __restrict__ xv,
    const u16* __restrict__ Wq, const u16* __restrict__ Wk, const u16* __restrict__ Wv,
    const float* __restrict__ bq, const float* __restrict__ bk, const float* __restrict__ bv,
    u16* __restrict__ Qh, u16* __restrict__ Kh, u16* __restrict__ Vt) {
  __shared__ u16 smA[128 * 32], smB[128 * 32];
  const int z = blockIdx.z;
  const u16* A = z == 0 ? xq : (z == 1 ? xk : xv);
  const u16* W = z == 0 ? Wq : (z == 1 ? Wk : Wv);
  const float* bias = z == 0 ? bq : (z == 1 ? bk : bv);
  u16* out = z == 0 ? Qh : (z == 1 ? Kh : Vt);
  const int gm0 = blockIdx.y * 128, gn0 = blockIdx.x * 128;
  f32x4 acc[4][4] = {};
  gemm_core_128(A, W, smA, smB, acc, gm0, gn0);

  const int tid = threadIdx.x;
  const int w = tid >> 6, l = tid & 63, g = l >> 4, r = l & 15;
  const int wm = w >> 1, wn = w & 1;
#pragma unroll
  for (int mt = 0; mt < 4; ++mt) {
#pragma unroll
    for (int nt = 0; nt < 4; ++nt) {
      int ncol = gn0 + wn * 64 + nt * 16 + r;
      int h = ncol >> 6, dk = ncol & 63;
      float bb = bias[ncol];
#pragma unroll
      for (int i = 0; i < 4; ++i) {
        int mrow = gm0 + wm * 64 + mt * 16 + g * 4 + i;
        int b = mrow >> 11, s = mrow & 2047;
        float v = acc[mt][nt][i] + bb;
        if (z < 2)
          out[(((size_t)b * Hh + h) * Ss + s) * DKc + dk] = f2bf(v);
        else
          out[(((size_t)b * Hh + h) * DKc + dk) * Ss + s] = f2bf(v);
      }
    }
  }
}

// ---------------- causal flash attention v2 ----------------
// Block = 4 waves, each wave 16 q-rows => QBLK=64. KVBLK=64 staged in LDS
// (double-buffered, chunk-XOR-swizzled). Block handles q-tiles {31-p, p}:
// exactly 33 kv-tiles per block (perfect causal load balance).
__global__ __launch_bounds__(256) void attn(
    const u16* __restrict__ Qh, const u16* __restrict__ Kh,
    const u16* __restrict__ Vt, u16* __restrict__ Ob) {
  __shared__ u16 smK[2][64 * 64];
  __shared__ u16 smV[2][64 * 64];
  __shared__ u16 smP[4][16 * 68];

  // XCD-aware remap: XCD k (= fid%8) owns bh in [4k, 4k+4) -> 2MB KV set per L2
  const int fid = blockIdx.y * 16 + blockIdx.x;
  const int xcd = fid & 7, slot = fid >> 3;
  const int bh = xcd * 4 + (slot >> 4);
  const int pair = slot & 15;
  const int bidx = bh >> 4, h = bh & 15;

  const int tid = threadIdx.x, w = tid >> 6, l = tid & 63;
  const int g = l >> 4, r = l & 15;

  const u16* Qb = Qh + (size_t)bh * Ss * DKc;
  const u16* Kb = Kh + (size_t)bh * Ss * DKc;
  const u16* Vb = Vt + (size_t)bh * DKc * Ss;
  u16* Pw = smP[w];

  // staging geometry: 256 threads x 16B = 4KB/issue; 2 issues per 8KB tile.
  // LDS linear slot (row, c): row = j*32 + tid>>3, c = tid&7.
  // Source chunk pre-swizzled: cg = c ^ (row&7)  (read side applies same XOR).
  const int srow0 = tid >> 3, schunk = tid & 7;

  auto stage = [&](int buf, int kb) {
#pragma unroll
    for (int j = 0; j < 2; ++j) {
      int row = j * 32 + srow0;
      int c = schunk ^ (row & 7);
      u16* dK = smK[buf] + (j * 256 + w * 64) * 8;
      u16* dV = smV[buf] + (j * 256 + w * 64) * 8;
      gload_lds16(Kb + (size_t)(kb + row) * DKc + c * 8, dK);
      gload_lds16(Vb + (size_t)row * Ss + kb + c * 8, dV);
    }
  };

  for (int t2 = 0; t2 < 2; ++t2) {
    const int qt = (t2 == 0) ? (31 - pair) : pair;
    const int q0 = qt * 64;
    const int ntile = qt + 1;
    const int qw = q0 + w * 16;

    short8 qf[2];
    qf[0] = *reinterpret_cast<const short8*>(Qb + (size_t)(qw + r) * DKc + g * 8);
    qf[1] = *reinterpret_cast<const short8*>(Qb + (size_t)(qw + r) * DKc + 32 + g * 8);

    f32x4 o[4] = {};
    float m_i[4], l_i[4];
#pragma unroll
    for (int i = 0; i < 4; ++i) { m_i[i] = -3e38f; l_i[i] = 0.f; }

    stage(0, 0);
    for (int kt = 0; kt < ntile; ++kt) {
      const int buf = kt & 1;
      const int kb = kt * 64;
      const bool diag = (kt == qt);
      __syncthreads();                          // tile kt staged
      if (kt + 1 < ntile) stage(buf ^ 1, kb + 64);

      // QK^T: 16q x 64kv, K from LDS (swizzled chunks)
      f32x4 s[4] = {};
#pragma unroll
      for (int ks = 0; ks < 2; ++ks)
#pragma unroll
        for (int nt = 0; nt < 4; ++nt) {
          int row = nt * 16 + r;
          int ch = (ks * 4 + g) ^ (row & 7);
          short8 kf = *reinterpret_cast<const short8*>(&smK[buf][row * 64 + ch * 8]);
          s[nt] = mfma16(qf[ks], kf, s[nt]);
        }

      // online softmax over 64 kv
#pragma unroll
      for (int i = 0; i < 4; ++i) {
        float v0 = s[0][i] * 0.125f, v1 = s[1][i] * 0.125f;
        float v2 = s[2][i] * 0.125f, v3 = s[3][i] * 0.125f;
        if (diag) {
          int q = qw + g * 4 + i;
          if (kb + r > q)      v0 = -1e30f;
          if (kb + 16 + r > q) v1 = -1e30f;
          if (kb + 32 + r > q) v2 = -1e30f;
          if (kb + 48 + r > q) v3 = -1e30f;
        }
        float mx = fmaxf(fmaxf(v0, v1), fmaxf(v2, v3));
        mx = fmaxf(mx, __shfl_xor(mx, 1));
        mx = fmaxf(mx, __shfl_xor(mx, 2));
        mx = fmaxf(mx, __shfl_xor(mx, 4));
        mx = fmaxf(mx, __shfl_xor(mx, 8));
        float mn = fmaxf(m_i[i], mx);
        float f = __expf(m_i[i] - mn);
        m_i[i] = mn;
        float p0 = __expf(v0 - mn), p1 = __expf(v1 - mn);
        float p2 = __expf(v2 - mn), p3 = __expf(v3 - mn);
        float rs = (p0 + p1) + (p2 + p3);
        rs += __shfl_xor(rs, 1);
        rs += __shfl_xor(rs, 2);
        rs += __shfl_xor(rs, 4);
        rs += __shfl_xor(rs, 8);
        l_i[i] = l_i[i] * f + rs;
        o[0][i] *= f; o[1][i] *= f; o[2][i] *= f; o[3][i] *= f;
        int prow = (g * 4 + i) * 68;
        Pw[prow + r]      = f2bf(p0);
        Pw[prow + 16 + r] = f2bf(p1);
        Pw[prow + 32 + r] = f2bf(p2);
        Pw[prow + 48 + r] = f2bf(p3);
      }

      // PV: o[16q x 64d] += P[16q x 64kv] * V^T, V from LDS (swizzled chunks)
#pragma unroll
      for (int ks = 0; ks < 2; ++ks) {
        short8 pf = *reinterpret_cast<const short8*>(&Pw[r * 68 + ks * 32 + g * 8]);
#pragma unroll
        for (int dt = 0; dt < 4; ++dt) {
          int row = dt * 16 + r;
          int ch = (ks * 4 + g) ^ (row & 7);
          short8 vf = *reinterpret_cast<const short8*>(&smV[buf][row * 64 + ch * 8]);
          o[dt] = mfma16(pf, vf, o[dt]);
        }
      }
      __syncthreads();                          // reads done before overwrite
    }

    // epilogue for this q-tile
#pragma unroll
    for (int i = 0; i < 4; ++i) {
      float inv = 1.f / l_i[i];
      size_t srow = (size_t)bidx * Ss + qw + g * 4 + i;
#pragma unroll
      for (int dt = 0; dt < 4; ++dt)
        Ob[srow * Dd + h * DKc + dt * 16 + r] = f2bf(o[dt][i] * inv);
    }
  }
}

// ---------------- output projection: bf16 A,W -> fp32 out + bias ----------------
__global__ __launch_bounds__(256) void gemm_out(
    const u16* __restrict__ Ob, const u16* __restrict__ Wo,
    const float* __restrict__ bo, float* __restrict__ out) {
  __shared__ u16 smA[128 * 32], smB[128 * 32];
  const int gm0 = blockIdx.y * 128, gn0 = blockIdx.x * 128;
  f32x4 acc[4][4] = {};
  gemm_core_128(Ob, Wo, smA, smB, acc, gm0, gn0);

  const int tid = threadIdx.x;
  const int w = tid >> 6, l = tid & 63, g = l >> 4, r = l & 15;
  const int wm = w >> 1, wn = w & 1;
#pragma unroll
  for (int mt = 0; mt < 4; ++mt) {
#pragma unroll
    for (int nt = 0; nt < 4; ++nt) {
      int ncol = gn0 + wn * 64 + nt * 16 + r;
      float bb = bo[ncol];
#pragma unroll
      for (int i = 0; i < 4; ++i) {
        int mrow = gm0 + wm * 64 + mt * 16 + g * 4 + i;
        out[(size_t)mrow * Dd + ncol] = acc[mt][nt][i] + bb;
      }
    }
  }
}

extern "C" void kernel_launch(void* const* d_in, const int* in_sizes, int n_in,
                              void* d_out, int out_size, void* d_ws, size_t ws_size,
                              hipStream_t stream) {
  const float* q    = (const float*)d_in[0];
  const float* k    = (const float*)d_in[1];
  const float* v    = (const float*)d_in[2];
  // d_in[3] = mask (causal tril) — handled analytically
  const float* wq_w = (const float*)d_in[4];
  const float* wq_b = (const float*)d_in[5];
  const float* wk_w = (const float*)d_in[6];
  const float* wk_b = (const float*)d_in[7];
  const float* wv_w = (const float*)d_in[8];
  const float* wv_b = (const float*)d_in[9];
  const float* wo_w = (const float*)d_in[10];
  const float* wo_b = (const float*)d_in[11];

  char* ws = (char*)d_ws;
  u16* xq  = (u16*)(ws + 0);
  u16* xk  = (u16*)(ws + 8388608);
  u16* xv  = (u16*)(ws + 16777216);
  u16* Wqb = (u16*)(ws + 25165824);
  u16* Wkb = (u16*)(ws + 27262976);
  u16* Wvb = (u16*)(ws + 29360128);
  u16* Wob = (u16*)(ws + 31457280);
  u16* Qh  = (u16*)(ws + 33554432);
  u16* Kh  = (u16*)(ws + 41943040);
  u16* Vt  = (u16*)(ws + 50331648);
  u16* Ob  = (u16*)(ws + 0);        // alias xq: dead after projections

  CvtArgs ca;
  ca.in[0] = q;    ca.out[0] = xq;  ca.n[0] = 4194304;
  ca.in[1] = k;    ca.out[1] = xk;  ca.n[1] = 4194304;
  ca.in[2] = v;    ca.out[2] = xv;  ca.n[2] = 4194304;
  ca.in[3] = wq_w; ca.out[3] = Wqb; ca.n[3] = 1048576;
  ca.in[4] = wk_w; ca.out[4] = Wkb; ca.n[4] = 1048576;
  ca.in[5] = wv_w; ca.out[5] = Wvb; ca.n[5] = 1048576;
  ca.in[6] = wo_w; ca.out[6] = Wob; ca.n[6] = 1048576;

  cvt_all<<<dim3(4096, 1, 7), 256, 0, stream>>>(ca);
  proj_qkv<<<dim3(8, 32, 3), 256, 0, stream>>>(xq, xk, xv, Wqb, Wkb, Wvb,
                                               wq_b, wk_b, wv_b, Qh, Kh, Vt);
  attn<<<dim3(16, 32), 256, 0, stream>>>(Qh, Kh, Vt, Ob);
  gemm_out<<<dim3(8, 32), 256, 0, stream>>>(Ob, Wob, wo_b, (float*)d_out);
}

// Round 3
// 141.025 us; speedup vs baseline: 2.2163x; 1.2043x over previous
//
#include <hip/hip_runtime.h>

#define DEV __device__ __forceinline__

typedef __attribute__((ext_vector_type(8))) short short8;
typedef __attribute__((ext_vector_type(4))) float f32x4;
typedef __bf16 bf16x8 __attribute__((ext_vector_type(8)));
typedef unsigned int u32;
typedef unsigned short u16;

constexpr int Bb = 2, Ss = 2048, Dd = 1024, Hh = 16, DKc = 64;
constexpr int Kk = 1024;   // inner dim of all projection GEMMs

// log2(e)/8: folds the 1/sqrt(DK) score scale AND the exp->exp2 conversion into Q
#define QSCALE 0.1803368801111204f

// ---- fp32 <-> bf16 (RNE), no hip_bf16 dependency ----
DEV u16 f2bf(float f) {
  u32 u = __builtin_bit_cast(u32, f);
  u32 r = (u + 0x7fffu + ((u >> 16) & 1u)) >> 16;
  return (u16)r;
}

DEV u32 pk_bf16(float lo, float hi) {
  u32 w;
  asm("v_cvt_pk_bf16_f32 %0, %1, %2" : "=v"(w) : "v"(lo), "v"(hi));
  return w;
}

DEV f32x4 mfma16(short8 a, short8 b, f32x4 c) {
  return __builtin_amdgcn_mfma_f32_16x16x32_bf16(
      __builtin_bit_cast(bf16x8, a), __builtin_bit_cast(bf16x8, b), c, 0, 0, 0);
}

DEV void gload_lds16(const u16* g, u16* lds) {
  __builtin_amdgcn_global_load_lds(
      (const __attribute__((address_space(1))) u32*)g,
      (__attribute__((address_space(3))) u32*)lds, 16, 0, 0);
}

// ---------------- fp32 -> bf16 conversion (7 tensors in one launch) ----------------
struct CvtArgs {
  const float* in[7];
  u16* out[7];
  int n[7];
};

__global__ __launch_bounds__(256) void cvt_all(CvtArgs a) {
  int z = blockIdx.z;
  int i = (blockIdx.x * 256 + threadIdx.x) * 4;
  if (i >= a.n[z]) return;
  float4 v = *reinterpret_cast<const float4*>(a.in[z] + i);
  ushort4 o;
  o.x = f2bf(v.x); o.y = f2bf(v.y); o.z = f2bf(v.z); o.w = f2bf(v.w);
  *reinterpret_cast<ushort4*>(a.out[z] + i) = o;
}

// ---------------- shared 128x128xK GEMM core (A, Bt both row-major [rows][K] bf16) ----
DEV void gemm_core_128(const u16* __restrict__ A, const u16* __restrict__ Bt,
                       u16* smA, u16* smB, f32x4 acc[4][4], int gm0, int gn0) {
  const int tid = threadIdx.x;
  const int w = tid >> 6, l = tid & 63;
  const int g = l >> 4, r = l & 15;
  const int wm = w >> 1, wn = w & 1;
  const int srow = l >> 2, scol = (l & 3) * 8;  // staging: 16 rows x 32 cols per 1KB chunk

  auto stage = [&](int kt) {
    int kb = kt * 32;
#pragma unroll
    for (int cc = 0; cc < 2; ++cc) {
      int c = w + cc * 4;                      // 8 chunks of 16 rows, 2 per wave
      gload_lds16(A + (size_t)(gm0 + c * 16 + srow) * Kk + kb + scol, smA + c * 512);
      gload_lds16(Bt + (size_t)(gn0 + c * 16 + srow) * Kk + kb + scol, smB + c * 512);
    }
  };

  stage(0);
  for (int kt = 0; kt < Kk / 32; ++kt) {
    __syncthreads();          // staging of tile kt complete (vmcnt drained)
    short8 af[4], bf_[4];
#pragma unroll
    for (int t = 0; t < 4; ++t) {
      af[t]  = *reinterpret_cast<const short8*>(smA + ((wm * 64 + t * 16 + r) * 32 + g * 8));
      bf_[t] = *reinterpret_cast<const short8*>(smB + ((wn * 64 + t * 16 + r) * 32 + g * 8));
    }
#pragma unroll
    for (int mt = 0; mt < 4; ++mt)
#pragma unroll
      for (int nt = 0; nt < 4; ++nt)
        acc[mt][nt] = mfma16(af[mt], bf_[nt], acc[mt][nt]);
    __syncthreads();          // all waves done reading before overwrite
    if (kt + 1 < Kk / 32) stage(kt + 1);
  }
}

// ---------------- QKV projection: z=0 Q (pre-scaled by QSCALE), z=1 K -> (B,H,S,DK);
// z=2 V -> (B,H,DK,S) ----
__global__ __launch_bounds__(256) void proj_qkv(
    const u16* __restrict__ xq, const u16* __restrict__ xk, const u16* __restrict__ xv,
    const u16* __restrict__ Wq, const u16* __restrict__ Wk, const u16* __restrict__ Wv,
    const float* __restrict__ bq, const float* __restrict__ bk, const float* __restrict__ bv,
    u16* __restrict__ Qh, u16* __restrict__ Kh, u16* __restrict__ Vt) {
  __shared__ u16 smA[128 * 32], smB[128 * 32];
  const int z = blockIdx.z;
  const u16* A = z == 0 ? xq : (z == 1 ? xk : xv);
  const u16* W = z == 0 ? Wq : (z == 1 ? Wk : Wv);
  const float* bias = z == 0 ? bq : (z == 1 ? bk : bv);
  u16* out = z == 0 ? Qh : (z == 1 ? Kh : Vt);
  const float sc = z == 0 ? QSCALE : 1.0f;
  const int gm0 = blockIdx.y * 128, gn0 = blockIdx.x * 128;
  f32x4 acc[4][4] = {};
  gemm_core_128(A, W, smA, smB, acc, gm0, gn0);

  const int tid = threadIdx.x;
  const int w = tid >> 6, l = tid & 63, g = l >> 4, r = l & 15;
  const int wm = w >> 1, wn = w & 1;
#pragma unroll
  for (int mt = 0; mt < 4; ++mt) {
#pragma unroll
    for (int nt = 0; nt < 4; ++nt) {
      int ncol = gn0 + wn * 64 + nt * 16 + r;
      int h = ncol >> 6, dk = ncol & 63;
      float bb = bias[ncol];
#pragma unroll
      for (int i = 0; i < 4; ++i) {
        int mrow = gm0 + wm * 64 + mt * 16 + g * 4 + i;
        int b = mrow >> 11, s = mrow & 2047;
        float v = (acc[mt][nt][i] + bb) * sc;
        if (z < 2)
          out[(((size_t)b * Hh + h) * Ss + s) * DKc + dk] = f2bf(v);
        else
          out[(((size_t)b * Hh + h) * DKc + dk) * Ss + s] = f2bf(v);
      }
    }
  }
}

// ---------------- causal flash attention v3: swapped QK^T, in-lane softmax ----------
// Block = 4 waves x 16 q-rows => QBLK=64. KVBLK=64 in LDS (dbuf, XOR-swizzled).
// Block handles q-tiles {31-p, p}: exactly 33 kv-tiles per block.
// Swapped mfma(K,Q): lane (g,r) holds S^T[kv = nt*16+g*4+i][q = qw+r] -> row softmax
// is 15 in-lane ops + 2 shuffles. PV as O^T = mfma(V^T, P); P transposed via wave-
// private LDS tile (stride 70 u16 -> <=2-way banks).
__global__ __launch_bounds__(256) void attn(
    const u16* __restrict__ Qh, const u16* __restrict__ Kh,
    const u16* __restrict__ Vt, u16* __restrict__ Ob) {
  __shared__ u16 smK[2][64 * 64];
  __shared__ u16 smV[2][64 * 64];
  __shared__ u16 smP[4][16 * 70];

  // XCD-aware remap: XCD k (= fid%8) owns bh in [4k, 4k+4) -> 2MB KV set per L2
  const int fid = blockIdx.y * 16 + blockIdx.x;
  const int xcd = fid & 7, slot = fid >> 3;
  const int bh = xcd * 4 + (slot >> 4);
  const int pair = slot & 15;
  const int bidx = bh >> 4, h = bh & 15;

  const int tid = threadIdx.x, w = tid >> 6, l = tid & 63;
  const int g = l >> 4, r = l & 15;

  const u16* Qb = Qh + (size_t)bh * Ss * DKc;
  const u16* Kb = Kh + (size_t)bh * Ss * DKc;
  const u16* Vb = Vt + (size_t)bh * DKc * Ss;
  u16* Pw = smP[w];

  const int srow0 = tid >> 3, schunk = tid & 7;

  auto stage = [&](int buf, int kb) {
#pragma unroll
    for (int j = 0; j < 2; ++j) {
      int row = j * 32 + srow0;
      int c = schunk ^ (row & 7);
      u16* dK = smK[buf] + (j * 256 + w * 64) * 8;
      u16* dV = smV[buf] + (j * 256 + w * 64) * 8;
      gload_lds16(Kb + (size_t)(kb + row) * DKc + c * 8, dK);
      gload_lds16(Vb + (size_t)row * Ss + kb + c * 8, dV);
    }
  };

  for (int t2 = 0; t2 < 2; ++t2) {
    const int qt = (t2 == 0) ? (31 - pair) : pair;
    const int ntile = qt + 1;
    const int qw = qt * 64 + w * 16;
    const int q = qw + r;                 // this lane's q row

    stage(0, 0);

    short8 qf[2];
    qf[0] = *reinterpret_cast<const short8*>(Qb + (size_t)q * DKc + g * 8);
    qf[1] = *reinterpret_cast<const short8*>(Qb + (size_t)q * DKc + 32 + g * 8);

    f32x4 o[4] = {};
    float m_s = -3e38f, l_s = 0.f;

    for (int kt = 0; kt < ntile; ++kt) {
      const int buf = kt & 1;
      const int kb = kt * 64;
      const bool diag = (kt == qt);
      __syncthreads();                          // tile kt staged
      if (kt + 1 < ntile) stage(buf ^ 1, kb + 64);

      // QK^T swapped: st[nt] = S^T tile, rows kv, cols q (log2-scaled via QSCALE)
      f32x4 st[4] = {};
      __builtin_amdgcn_s_setprio(1);
#pragma unroll
      for (int ks = 0; ks < 2; ++ks)
#pragma unroll
        for (int nt = 0; nt < 4; ++nt) {
          int row = nt * 16 + r;
          int ch = (ks * 4 + g) ^ (row & 7);
          short8 kf = *reinterpret_cast<const short8*>(&smK[buf][row * 64 + ch * 8]);
          st[nt] = mfma16(kf, qf[ks], st[nt]);
        }
      __builtin_amdgcn_s_setprio(0);

      if (diag) {
        int qloc = w * 16 + r;
#pragma unroll
        for (int nt = 0; nt < 4; ++nt)
#pragma unroll
          for (int i = 0; i < 4; ++i)
            if (nt * 16 + g * 4 + i > qloc) st[nt][i] = -1e30f;
      }

      // in-lane softmax for this lane's q-row (16 kv values, then 2 cross-g shuffles)
      float mx0 = fmaxf(fmaxf(st[0][0], st[0][1]), fmaxf(st[0][2], st[0][3]));
      float mx1 = fmaxf(fmaxf(st[1][0], st[1][1]), fmaxf(st[1][2], st[1][3]));
      float mx2 = fmaxf(fmaxf(st[2][0], st[2][1]), fmaxf(st[2][2], st[2][3]));
      float mx3 = fmaxf(fmaxf(st[3][0], st[3][1]), fmaxf(st[3][2], st[3][3]));
      float mx = fmaxf(fmaxf(mx0, mx1), fmaxf(mx2, mx3));
      mx = fmaxf(mx, __shfl_xor(mx, 16));
      mx = fmaxf(mx, __shfl_xor(mx, 32));
      float mn = fmaxf(m_s, mx);
      float f = __builtin_amdgcn_exp2f(m_s - mn);
      m_s = mn;
      float rs = 0.f;
#pragma unroll
      for (int nt = 0; nt < 4; ++nt) {
        float p0 = __builtin_amdgcn_exp2f(st[nt][0] - mn);
        float p1 = __builtin_amdgcn_exp2f(st[nt][1] - mn);
        float p2 = __builtin_amdgcn_exp2f(st[nt][2] - mn);
        float p3 = __builtin_amdgcn_exp2f(st[nt][3] - mn);
        rs += (p0 + p1) + (p2 + p3);
        // pack pairs -> LDS transpose tile: word covers kv nt*16+g*4+{2c,2c+1}
        *reinterpret_cast<u32*>(&Pw[r * 70 + nt * 16 + g * 4])     = pk_bf16(p0, p1);
        *reinterpret_cast<u32*>(&Pw[r * 70 + nt * 16 + g * 4 + 2]) = pk_bf16(p2, p3);
      }
      rs += __shfl_xor(rs, 16);
      rs += __shfl_xor(rs, 32);
      l_s = l_s * f + rs;
#pragma unroll
      for (int dt = 0; dt < 4; ++dt) {
        o[dt][0] *= f; o[dt][1] *= f; o[dt][2] *= f; o[dt][3] *= f;
      }

      // PV: O^T[d][q] += V^T[d][kv] * P^T[kv][q]  (A = V^T rows, B = P rows)
      __builtin_amdgcn_s_setprio(1);
#pragma unroll
      for (int ks = 0; ks < 2; ++ks) {
        short8 pf = *reinterpret_cast<const short8*>(&Pw[r * 70 + ks * 32 + g * 8]);
#pragma unroll
        for (int dt = 0; dt < 4; ++dt) {
          int row = dt * 16 + r;
          int ch = (ks * 4 + g) ^ (row & 7);
          short8 vf = *reinterpret_cast<const short8*>(&smV[buf][row * 64 + ch * 8]);
          o[dt] = mfma16(vf, pf, o[dt]);
        }
      }
      __builtin_amdgcn_s_setprio(0);
      __syncthreads();                          // reads done before overwrite
    }

    // epilogue: lane (g,r) holds O^T[d = dt*16+g*4+i][q]
    float inv = 1.f / l_s;
    size_t ro = ((size_t)bidx * Ss + q) * Dd + h * DKc;
#pragma unroll
    for (int dt = 0; dt < 4; ++dt) {
      ushort4 ov;
      ov.x = f2bf(o[dt][0] * inv);
      ov.y = f2bf(o[dt][1] * inv);
      ov.z = f2bf(o[dt][2] * inv);
      ov.w = f2bf(o[dt][3] * inv);
      *reinterpret_cast<ushort4*>(&Ob[ro + dt * 16 + g * 4]) = ov;
    }
  }
}

// ---------------- output projection: bf16 A,W -> fp32 out + bias ----------------
__global__ __launch_bounds__(256) void gemm_out(
    const u16* __restrict__ Ob, const u16* __restrict__ Wo,
    const float* __restrict__ bo, float* __restrict__ out) {
  __shared__ u16 smA[128 * 32], smB[128 * 32];
  const int gm0 = blockIdx.y * 128, gn0 = blockIdx.x * 128;
  f32x4 acc[4][4] = {};
  gemm_core_128(Ob, Wo, smA, smB, acc, gm0, gn0);

  const int tid = threadIdx.x;
  const int w = tid >> 6, l = tid & 63, g = l >> 4, r = l & 15;
  const int wm = w >> 1, wn = w & 1;
#pragma unroll
  for (int mt = 0; mt < 4; ++mt) {
#pragma unroll
    for (int nt = 0; nt < 4; ++nt) {
      int ncol = gn0 + wn * 64 + nt * 16 + r;
      float bb = bo[ncol];
#pragma unroll
      for (int i = 0; i < 4; ++i) {
        int mrow = gm0 + wm * 64 + mt * 16 + g * 4 + i;
        out[(size_t)mrow * Dd + ncol] = acc[mt][nt][i] + bb;
      }
    }
  }
}

extern "C" void kernel_launch(void* const* d_in, const int* in_sizes, int n_in,
                              void* d_out, int out_size, void* d_ws, size_t ws_size,
                              hipStream_t stream) {
  const float* q    = (const float*)d_in[0];
  const float* k    = (const float*)d_in[1];
  const float* v    = (const float*)d_in[2];
  // d_in[3] = mask (causal tril) — handled analytically
  const float* wq_w = (const float*)d_in[4];
  const float* wq_b = (const float*)d_in[5];
  const float* wk_w = (const float*)d_in[6];
  const float* wk_b = (const float*)d_in[7];
  const float* wv_w = (const float*)d_in[8];
  const float* wv_b = (const float*)d_in[9];
  const float* wo_w = (const float*)d_in[10];
  const float* wo_b = (const float*)d_in[11];

  char* ws = (char*)d_ws;
  u16* xq  = (u16*)(ws + 0);
  u16* xk  = (u16*)(ws + 8388608);
  u16* xv  = (u16*)(ws + 16777216);
  u16* Wqb = (u16*)(ws + 25165824);
  u16* Wkb = (u16*)(ws + 27262976);
  u16* Wvb = (u16*)(ws + 29360128);
  u16* Wob = (u16*)(ws + 31457280);
  u16* Qh  = (u16*)(ws + 33554432);
  u16* Kh  = (u16*)(ws + 41943040);
  u16* Vt  = (u16*)(ws + 50331648);
  u16* Ob  = (u16*)(ws + 0);        // alias xq: dead after projections

  CvtArgs ca;
  ca.in[0] = q;    ca.out[0] = xq;  ca.n[0] = 4194304;
  ca.in[1] = k;    ca.out[1] = xk;  ca.n[1] = 4194304;
  ca.in[2] = v;    ca.out[2] = xv;  ca.n[2] = 4194304;
  ca.in[3] = wq_w; ca.out[3] = Wqb; ca.n[3] = 1048576;
  ca.in[4] = wk_w; ca.out[4] = Wkb; ca.n[4] = 1048576;
  ca.in[5] = wv_w; ca.out[5] = Wvb; ca.n[5] = 1048576;
  ca.in[6] = wo_w; ca.out[6] = Wob; ca.n[6] = 1048576;

  cvt_all<<<dim3(4096, 1, 7), 256, 0, stream>>>(ca);
  proj_qkv<<<dim3(8, 32, 3), 256, 0, stream>>>(xq, xk, xv, Wqb, Wkb, Wvb,
                                               wq_b, wk_b, wv_b, Qh, Kh, Vt);
  attn<<<dim3(16, 32), 256, 0, stream>>>(Qh, Kh, Vt, Ob);
  gemm_out<<<dim3(8, 32), 256, 0, stream>>>(Ob, Wob, wo_b, (float*)d_out);
}

// Round 4
// 137.799 us; speedup vs baseline: 2.2682x; 1.0234x over previous
//
#include <hip/hip_runtime.h>

#define DEV __device__ __forceinline__

typedef __attribute__((ext_vector_type(8))) short short8;
typedef __attribute__((ext_vector_type(4))) float f32x4;
typedef __bf16 bf16x8 __attribute__((ext_vector_type(8)));
typedef unsigned int u32;
typedef unsigned short u16;

constexpr int Bb = 2, Ss = 2048, Dd = 1024, Hh = 16, DKc = 64;
constexpr int Kk = 1024;   // inner dim of all projection GEMMs

// log2(e)/8: folds the 1/sqrt(DK) score scale AND the exp->exp2 conversion into Q
#define QSCALE 0.1803368801111204f

// ---- fp32 <-> bf16 (RNE), no hip_bf16 dependency ----
DEV u16 f2bf(float f) {
  u32 u = __builtin_bit_cast(u32, f);
  u32 r = (u + 0x7fffu + ((u >> 16) & 1u)) >> 16;
  return (u16)r;
}

DEV u32 pk_bf16(float lo, float hi) {
  u32 w;
  asm("v_cvt_pk_bf16_f32 %0, %1, %2" : "=v"(w) : "v"(lo), "v"(hi));
  return w;
}

DEV f32x4 mfma16(short8 a, short8 b, f32x4 c) {
  return __builtin_amdgcn_mfma_f32_16x16x32_bf16(
      __builtin_bit_cast(bf16x8, a), __builtin_bit_cast(bf16x8, b), c, 0, 0, 0);
}

DEV void gload_lds16(const u16* g, u16* lds) {
  __builtin_amdgcn_global_load_lds(
      (const __attribute__((address_space(1))) u32*)g,
      (__attribute__((address_space(3))) u32*)lds, 16, 0, 0);
}

// ---------------- fp32 -> bf16 conversion (7 tensors in one launch) ----------------
struct CvtArgs {
  const float* in[7];
  u16* out[7];
  int n[7];
};

__global__ __launch_bounds__(256) void cvt_all(CvtArgs a) {
  int z = blockIdx.z;
  int i = (blockIdx.x * 256 + threadIdx.x) * 4;
  if (i >= a.n[z]) return;
  float4 v = *reinterpret_cast<const float4*>(a.in[z] + i);
  ushort4 o;
  o.x = f2bf(v.x); o.y = f2bf(v.y); o.z = f2bf(v.z); o.w = f2bf(v.w);
  *reinterpret_cast<ushort4*>(a.out[z] + i) = o;
}

// ---------------- shared 128x128xK GEMM core (A, Bt both row-major [rows][K] bf16) ----
DEV void gemm_core_128(const u16* __restrict__ A, const u16* __restrict__ Bt,
                       u16* smA, u16* smB, f32x4 acc[4][4], int gm0, int gn0) {
  const int tid = threadIdx.x;
  const int w = tid >> 6, l = tid & 63;
  const int g = l >> 4, r = l & 15;
  const int wm = w >> 1, wn = w & 1;
  const int srow = l >> 2, scol = (l & 3) * 8;  // staging: 16 rows x 32 cols per 1KB chunk

  auto stage = [&](int kt) {
    int kb = kt * 32;
#pragma unroll
    for (int cc = 0; cc < 2; ++cc) {
      int c = w + cc * 4;                      // 8 chunks of 16 rows, 2 per wave
      gload_lds16(A + (size_t)(gm0 + c * 16 + srow) * Kk + kb + scol, smA + c * 512);
      gload_lds16(Bt + (size_t)(gn0 + c * 16 + srow) * Kk + kb + scol, smB + c * 512);
    }
  };

  stage(0);
  for (int kt = 0; kt < Kk / 32; ++kt) {
    __syncthreads();          // staging of tile kt complete (vmcnt drained)
    short8 af[4], bf_[4];
#pragma unroll
    for (int t = 0; t < 4; ++t) {
      af[t]  = *reinterpret_cast<const short8*>(smA + ((wm * 64 + t * 16 + r) * 32 + g * 8));
      bf_[t] = *reinterpret_cast<const short8*>(smB + ((wn * 64 + t * 16 + r) * 32 + g * 8));
    }
#pragma unroll
    for (int mt = 0; mt < 4; ++mt)
#pragma unroll
      for (int nt = 0; nt < 4; ++nt)
        acc[mt][nt] = mfma16(af[mt], bf_[nt], acc[mt][nt]);
    __syncthreads();          // all waves done reading before overwrite
    if (kt + 1 < Kk / 32) stage(kt + 1);
  }
}

// ---------------- QKV projection: z=0 Q (pre-scaled by QSCALE), z=1 K -> (B,H,S,DK);
// z=2 V -> (B,H,DK,S) ----
__global__ __launch_bounds__(256) void proj_qkv(
    const u16* __restrict__ xq, const u16* __restrict__ xk, const u16* __restrict__ xv,
    const u16* __restrict__ Wq, const u16* __restrict__ Wk, const u16* __restrict__ Wv,
    const float* __restrict__ bq, const float* __restrict__ bk, const float* __restrict__ bv,
    u16* __restrict__ Qh, u16* __restrict__ Kh, u16* __restrict__ Vt) {
  __shared__ u16 smA[128 * 32], smB[128 * 32];
  const int z = blockIdx.z;
  const u16* A = z == 0 ? xq : (z == 1 ? xk : xv);
  const u16* W = z == 0 ? Wq : (z == 1 ? Wk : Wv);
  const float* bias = z == 0 ? bq : (z == 1 ? bk : bv);
  u16* out = z == 0 ? Qh : (z == 1 ? Kh : Vt);
  const float sc = z == 0 ? QSCALE : 1.0f;
  const int gm0 = blockIdx.y * 128, gn0 = blockIdx.x * 128;
  f32x4 acc[4][4] = {};
  gemm_core_128(A, W, smA, smB, acc, gm0, gn0);

  const int tid = threadIdx.x;
  const int w = tid >> 6, l = tid & 63, g = l >> 4, r = l & 15;
  const int wm = w >> 1, wn = w & 1;
#pragma unroll
  for (int mt = 0; mt < 4; ++mt) {
#pragma unroll
    for (int nt = 0; nt < 4; ++nt) {
      int ncol = gn0 + wn * 64 + nt * 16 + r;
      int h = ncol >> 6, dk = ncol & 63;
      float bb = bias[ncol];
#pragma unroll
      for (int i = 0; i < 4; ++i) {
        int mrow = gm0 + wm * 64 + mt * 16 + g * 4 + i;
        int b = mrow >> 11, s = mrow & 2047;
        float v = (acc[mt][nt][i] + bb) * sc;
        if (z < 2)
          out[(((size_t)b * Hh + h) * Ss + s) * DKc + dk] = f2bf(v);
        else
          out[(((size_t)b * Hh + h) * DKc + dk) * Ss + s] = f2bf(v);
      }
    }
  }
}

// ---------------- causal flash attention v4 ----------------
// v3 + : triple-buffered K/V staging with raw s_barrier + counted vmcnt (loads get
// ~2 tiles of compute to land; ONE barrier per tile), defer-max (THR=8 in log2
// domain), lazy per-lane l partial (cross-lane reduce once in epilogue). Steady
// tiles execute zero shuffles.
__global__ __launch_bounds__(256) void attn(
    const u16* __restrict__ Qh, const u16* __restrict__ Kh,
    const u16* __restrict__ Vt, u16* __restrict__ Ob) {
  __shared__ u16 smK[3][64 * 64];
  __shared__ u16 smV[3][64 * 64];
  __shared__ u16 smP[4][16 * 70];

  // XCD-aware remap: XCD k (= fid%8) owns bh in [4k, 4k+4) -> 2MB KV set per L2
  const int fid = blockIdx.y * 16 + blockIdx.x;
  const int xcd = fid & 7, slot = fid >> 3;
  const int bh = xcd * 4 + (slot >> 4);
  const int pair = slot & 15;
  const int bidx = bh >> 4, h = bh & 15;

  const int tid = threadIdx.x, w = tid >> 6, l = tid & 63;
  const int g = l >> 4, r = l & 15;

  const u16* Qb = Qh + (size_t)bh * Ss * DKc;
  const u16* Kb = Kh + (size_t)bh * Ss * DKc;
  const u16* Vb = Vt + (size_t)bh * DKc * Ss;
  u16* Pw = smP[w];

  const int srow0 = tid >> 3, schunk = tid & 7;

  auto stage = [&](int buf, int kb) {
#pragma unroll
    for (int j = 0; j < 2; ++j) {
      int row = j * 32 + srow0;
      int c = schunk ^ (row & 7);
      u16* dK = smK[buf] + (j * 256 + w * 64) * 8;
      u16* dV = smV[buf] + (j * 256 + w * 64) * 8;
      gload_lds16(Kb + (size_t)(kb + row) * DKc + c * 8, dK);
      gload_lds16(Vb + (size_t)row * Ss + kb + c * 8, dV);
    }
  };

  for (int t2 = 0; t2 < 2; ++t2) {
    const int qt = (t2 == 0) ? (31 - pair) : pair;
    const int ntile = qt + 1;
    const int qw = qt * 64 + w * 16;
    const int q = qw + r;                 // this lane's q row

    if (t2) __builtin_amdgcn_s_barrier();   // all waves done reading bufs of t2=0

    short8 qf[2];
    qf[0] = *reinterpret_cast<const short8*>(Qb + (size_t)q * DKc + g * 8);
    qf[1] = *reinterpret_cast<const short8*>(Qb + (size_t)q * DKc + 32 + g * 8);

    stage(0, 0);
    if (ntile > 1) stage(1, 64);

    f32x4 o[4] = {};
    float m_s = -3e38f, l_s = 0.f;

    for (int kt = 0; kt < ntile; ++kt) {
      const int buf = kt % 3;
      const int kb = kt * 64;
      const bool diag = (kt == qt);

      // own stage(kt) loads complete (4 youngest = stage(kt+1) may stay in flight)
      if (kt + 1 < ntile) { asm volatile("s_waitcnt vmcnt(4)" ::: "memory"); }
      else                { asm volatile("s_waitcnt vmcnt(0)" ::: "memory"); }
      __builtin_amdgcn_s_barrier();         // all waves: tile kt staged, tile kt-1 reads done
      __builtin_amdgcn_sched_barrier(0);
      if (kt + 2 < ntile) stage((kt + 2) % 3, kb + 128);

      // QK^T swapped: st[nt] = S^T tile, rows kv, cols q (log2-scaled via QSCALE)
      f32x4 st[4] = {};
      __builtin_amdgcn_s_setprio(1);
#pragma unroll
      for (int ks = 0; ks < 2; ++ks)
#pragma unroll
        for (int nt = 0; nt < 4; ++nt) {
          int row = nt * 16 + r;
          int ch = (ks * 4 + g) ^ (row & 7);
          short8 kf = *reinterpret_cast<const short8*>(&smK[buf][row * 64 + ch * 8]);
          st[nt] = mfma16(kf, qf[ks], st[nt]);
        }
      __builtin_amdgcn_s_setprio(0);

      if (diag) {
        int qloc = w * 16 + r;
#pragma unroll
        for (int nt = 0; nt < 4; ++nt)
#pragma unroll
          for (int i = 0; i < 4; ++i)
            if (nt * 16 + g * 4 + i > qloc) st[nt][i] = -1e30f;
      }

      // in-lane partial max over this lane's 16 scores (v_max3-friendly tree)
      float mx0 = fmaxf(fmaxf(st[0][0], st[0][1]), fmaxf(st[0][2], st[0][3]));
      float mx1 = fmaxf(fmaxf(st[1][0], st[1][1]), fmaxf(st[1][2], st[1][3]));
      float mx2 = fmaxf(fmaxf(st[2][0], st[2][1]), fmaxf(st[2][2], st[2][3]));
      float mx3 = fmaxf(fmaxf(st[3][0], st[3][1]), fmaxf(st[3][2], st[3][3]));
      float mx = fmaxf(fmaxf(mx0, mx1), fmaxf(mx2, mx3));

      // defer-max: only rescale when some row's tile-max beats running max by >8
      // (log2 domain: P values stay <= 2^8, bf16/fp32 accum tolerate)
      if (__any(mx > m_s + 8.f)) {
        float mr = fmaxf(mx, __shfl_xor(mx, 16));
        mr = fmaxf(mr, __shfl_xor(mr, 32));      // row-wide max (4 g-lanes of same r)
        float mn = fmaxf(m_s, mr);
        float f = __builtin_amdgcn_exp2f(m_s - mn);
        m_s = mn;
        l_s *= f;
#pragma unroll
        for (int dt = 0; dt < 4; ++dt) {
          o[dt][0] *= f; o[dt][1] *= f; o[dt][2] *= f; o[dt][3] *= f;
        }
      }

#pragma unroll
      for (int nt = 0; nt < 4; ++nt) {
        float p0 = __builtin_amdgcn_exp2f(st[nt][0] - m_s);
        float p1 = __builtin_amdgcn_exp2f(st[nt][1] - m_s);
        float p2 = __builtin_amdgcn_exp2f(st[nt][2] - m_s);
        float p3 = __builtin_amdgcn_exp2f(st[nt][3] - m_s);
        l_s += (p0 + p1) + (p2 + p3);            // per-lane partial; reduced in epilogue
        // pack pairs -> LDS transpose tile: word covers kv nt*16+g*4+{2c,2c+1}
        *reinterpret_cast<u32*>(&Pw[r * 70 + nt * 16 + g * 4])     = pk_bf16(p0, p1);
        *reinterpret_cast<u32*>(&Pw[r * 70 + nt * 16 + g * 4 + 2]) = pk_bf16(p2, p3);
      }

      // PV: O^T[d][q] += V^T[d][kv] * P^T[kv][q]  (A = V^T rows, B = P rows)
      __builtin_amdgcn_s_setprio(1);
#pragma unroll
      for (int ks = 0; ks < 2; ++ks) {
        short8 pf = *reinterpret_cast<const short8*>(&Pw[r * 70 + ks * 32 + g * 8]);
#pragma unroll
        for (int dt = 0; dt < 4; ++dt) {
          int row = dt * 16 + r;
          int ch = (ks * 4 + g) ^ (row & 7);
          short8 vf = *reinterpret_cast<const short8*>(&smV[buf][row * 64 + ch * 8]);
          o[dt] = mfma16(vf, pf, o[dt]);
        }
      }
      __builtin_amdgcn_s_setprio(0);
    }

    // epilogue: lane (g,r) holds O^T[d = dt*16+g*4+i][q]; reduce partial l across g
    float lt = l_s;
    lt += __shfl_xor(lt, 16);
    lt += __shfl_xor(lt, 32);
    float inv = 1.f / lt;
    size_t ro = ((size_t)bidx * Ss + q) * Dd + h * DKc;
#pragma unroll
    for (int dt = 0; dt < 4; ++dt) {
      ushort4 ov;
      ov.x = f2bf(o[dt][0] * inv);
      ov.y = f2bf(o[dt][1] * inv);
      ov.z = f2bf(o[dt][2] * inv);
      ov.w = f2bf(o[dt][3] * inv);
      *reinterpret_cast<ushort4*>(&Ob[ro + dt * 16 + g * 4]) = ov;
    }
  }
}

// ---------------- output projection: bf16 A,W -> fp32 out + bias ----------------
__global__ __launch_bounds__(256) void gemm_out(
    const u16* __restrict__ Ob, const u16* __restrict__ Wo,
    const float* __restrict__ bo, float* __restrict__ out) {
  __shared__ u16 smA[128 * 32], smB[128 * 32];
  const int gm0 = blockIdx.y * 128, gn0 = blockIdx.x * 128;
  f32x4 acc[4][4] = {};
  gemm_core_128(Ob, Wo, smA, smB, acc, gm0, gn0);

  const int tid = threadIdx.x;
  const int w = tid >> 6, l = tid & 63, g = l >> 4, r = l & 15;
  const int wm = w >> 1, wn = w & 1;
#pragma unroll
  for (int mt = 0; mt < 4; ++mt) {
#pragma unroll
    for (int nt = 0; nt < 4; ++nt) {
      int ncol = gn0 + wn * 64 + nt * 16 + r;
      float bb = bo[ncol];
#pragma unroll
      for (int i = 0; i < 4; ++i) {
        int mrow = gm0 + wm * 64 + mt * 16 + g * 4 + i;
        out[(size_t)mrow * Dd + ncol] = acc[mt][nt][i] + bb;
      }
    }
  }
}

extern "C" void kernel_launch(void* const* d_in, const int* in_sizes, int n_in,
                              void* d_out, int out_size, void* d_ws, size_t ws_size,
                              hipStream_t stream) {
  const float* q    = (const float*)d_in[0];
  const float* k    = (const float*)d_in[1];
  const float* v    = (const float*)d_in[2];
  // d_in[3] = mask (causal tril) — handled analytically
  const float* wq_w = (const float*)d_in[4];
  const float* wq_b = (const float*)d_in[5];
  const float* wk_w = (const float*)d_in[6];
  const float* wk_b = (const float*)d_in[7];
  const float* wv_w = (const float*)d_in[8];
  const float* wv_b = (const float*)d_in[9];
  const float* wo_w = (const float*)d_in[10];
  const float* wo_b = (const float*)d_in[11];

  char* ws = (char*)d_ws;
  u16* xq  = (u16*)(ws + 0);
  u16* xk  = (u16*)(ws + 8388608);
  u16* xv  = (u16*)(ws + 16777216);
  u16* Wqb = (u16*)(ws + 25165824);
  u16* Wkb = (u16*)(ws + 27262976);
  u16* Wvb = (u16*)(ws + 29360128);
  u16* Wob = (u16*)(ws + 31457280);
  u16* Qh  = (u16*)(ws + 33554432);
  u16* Kh  = (u16*)(ws + 41943040);
  u16* Vt  = (u16*)(ws + 50331648);
  u16* Ob  = (u16*)(ws + 0);        // alias xq: dead after projections

  CvtArgs ca;
  ca.in[0] = q;    ca.out[0] = xq;  ca.n[0] = 4194304;
  ca.in[1] = k;    ca.out[1] = xk;  ca.n[1] = 4194304;
  ca.in[2] = v;    ca.out[2] = xv;  ca.n[2] = 4194304;
  ca.in[3] = wq_w; ca.out[3] = Wqb; ca.n[3] = 1048576;
  ca.in[4] = wk_w; ca.out[4] = Wkb; ca.n[4] = 1048576;
  ca.in[5] = wv_w; ca.out[5] = Wvb; ca.n[5] = 1048576;
  ca.in[6] = wo_w; ca.out[6] = Wob; ca.n[6] = 1048576;

  cvt_all<<<dim3(4096, 1, 7), 256, 0, stream>>>(ca);
  proj_qkv<<<dim3(8, 32, 3), 256, 0, stream>>>(xq, xk, xv, Wqb, Wkb, Wvb,
                                               wq_b, wk_b, wv_b, Qh, Kh, Vt);
  attn<<<dim3(16, 32), 256, 0, stream>>>(Qh, Kh, Vt, Ob);
  gemm_out<<<dim3(8, 32), 256, 0, stream>>>(Ob, Wob, wo_b, (float*)d_out);
}

// Round 5
// 112.660 us; speedup vs baseline: 2.7743x; 1.2231x over previous
//
#include <hip/hip_runtime.h>

#define DEV __device__ __forceinline__

typedef __attribute__((ext_vector_type(8))) short short8;
typedef __attribute__((ext_vector_type(4))) float f32x4;
typedef __bf16 bf16x8 __attribute__((ext_vector_type(8)));
typedef unsigned int u32;
typedef unsigned short u16;

constexpr int Bb = 2, Ss = 2048, Dd = 1024, Hh = 16, DKc = 64;
constexpr int Kk = 1024;   // inner dim of all projection GEMMs

// log2(e)/8: folds the 1/sqrt(DK) score scale AND the exp->exp2 conversion into Q
#define QSCALE 0.1803368801111204f

// ---- fp32 <-> bf16 (RNE), no hip_bf16 dependency ----
DEV u16 f2bf(float f) {
  u32 u = __builtin_bit_cast(u32, f);
  u32 r = (u + 0x7fffu + ((u >> 16) & 1u)) >> 16;
  return (u16)r;
}

DEV u32 pk_bf16(float lo, float hi) {
  u32 w;
  asm("v_cvt_pk_bf16_f32 %0, %1, %2" : "=v"(w) : "v"(lo), "v"(hi));
  return w;
}

DEV f32x4 mfma16(short8 a, short8 b, f32x4 c) {
  return __builtin_amdgcn_mfma_f32_16x16x32_bf16(
      __builtin_bit_cast(bf16x8, a), __builtin_bit_cast(bf16x8, b), c, 0, 0, 0);
}

DEV void gload_lds16(const u16* g, u16* lds) {
  __builtin_amdgcn_global_load_lds(
      (const __attribute__((address_space(1))) u32*)g,
      (__attribute__((address_space(3))) u32*)lds, 16, 0, 0);
}

// ---------------- fp32 -> bf16 conversion (7 tensors in one launch) ----------------
struct CvtArgs {
  const float* in[7];
  u16* out[7];
  int n[7];
};

__global__ __launch_bounds__(256) void cvt_all(CvtArgs a) {
  int z = blockIdx.z;
  int i = (blockIdx.x * 256 + threadIdx.x) * 4;
  if (i >= a.n[z]) return;
  float4 v = *reinterpret_cast<const float4*>(a.in[z] + i);
  ushort4 o;
  o.x = f2bf(v.x); o.y = f2bf(v.y); o.z = f2bf(v.z); o.w = f2bf(v.w);
  *reinterpret_cast<ushort4*>(a.out[z] + i) = o;
}

// ---------------- GEMM core v2: BM=MT*32 x BN=NT*32, BK=32, triple-buffered ----------
// One s_barrier per K-step; stage issued 2 steps ahead; counted vmcnt keeps the
// next stage's S loads in flight across the barrier (loads get ~2 compute phases).
// LDS tile layout == linear [row][32] (16x32 chunks), 2-way bank alias only.
template<int MT, int NT>
DEV void gemm_core(const u16* __restrict__ A, const u16* __restrict__ Bt,
                   u16* smA, u16* smB, f32x4 (&acc)[MT][NT], int gm0, int gn0) {
  constexpr int NSTEP = Kk / 32;
  constexpr int SA = MT * 1024;            // elements per A buffer
  constexpr int SB = NT * 1024;
  constexpr int S = MT / 2 + NT / 2;       // gloads per thread per stage
  const int tid = threadIdx.x;
  const int w = tid >> 6, l = tid & 63;
  const int g = (l >> 4) & 3, r = l & 15;
  const int wm = w >> 1, wn = w & 1;
  const int srow = l >> 2, scol = (l & 3) * 8;  // 16 rows x 32 cols per 1KB chunk

  auto stage = [&](int buf, int kt) {
    int kb = kt * 32;
#pragma unroll
    for (int cc = 0; cc < MT / 2; ++cc) {
      int c = w + cc * 4;
      gload_lds16(A + (size_t)(gm0 + c * 16 + srow) * Kk + kb + scol,
                  smA + buf * SA + c * 512);
    }
#pragma unroll
    for (int cc = 0; cc < NT / 2; ++cc) {
      int c = w + cc * 4;
      gload_lds16(Bt + (size_t)(gn0 + c * 16 + srow) * Kk + kb + scol,
                  smB + buf * SB + c * 512);
    }
  };

  stage(0, 0);
  stage(1, 1);
  for (int kt = 0; kt < NSTEP; ++kt) {
    const int buf = kt % 3;
    if (kt + 1 < NSTEP) {
      if constexpr (S == 4) asm volatile("s_waitcnt vmcnt(4)" ::: "memory");
      else                  asm volatile("s_waitcnt vmcnt(3)" ::: "memory");
    } else {
      asm volatile("s_waitcnt vmcnt(0)" ::: "memory");
    }
    __builtin_amdgcn_s_barrier();           // stage(kt) visible to all waves
    __builtin_amdgcn_sched_barrier(0);
    if (kt + 2 < NSTEP) stage((kt + 2) % 3, kt + 2);

    short8 af[MT], bf_[NT];
#pragma unroll
    for (int t = 0; t < MT; ++t)
      af[t] = *reinterpret_cast<const short8*>(
          smA + buf * SA + (wm * (MT * 16) + t * 16 + r) * 32 + g * 8);
#pragma unroll
    for (int t = 0; t < NT; ++t)
      bf_[t] = *reinterpret_cast<const short8*>(
          smB + buf * SB + (wn * (NT * 16) + t * 16 + r) * 32 + g * 8);
    __builtin_amdgcn_s_setprio(1);
#pragma unroll
    for (int mt = 0; mt < MT; ++mt)
#pragma unroll
      for (int nt = 0; nt < NT; ++nt)
        acc[mt][nt] = mfma16(af[mt], bf_[nt], acc[mt][nt]);
    __builtin_amdgcn_s_setprio(0);
  }
}

// ---------------- QKV projection: z=0 Q (pre-scaled by QSCALE), z=1 K -> (B,H,S,DK);
// z=2 V -> (B,H,DK,S) ----
__global__ __launch_bounds__(256, 3) void proj_qkv(
    const u16* __restrict__ xq, const u16* __restrict__ xk, const u16* __restrict__ xv,
    const u16* __restrict__ Wq, const u16* __restrict__ Wk, const u16* __restrict__ Wv,
    const float* __restrict__ bq, const float* __restrict__ bk, const float* __restrict__ bv,
    u16* __restrict__ Qh, u16* __restrict__ Kh, u16* __restrict__ Vt) {
  __shared__ u16 smA[3 * 128 * 32], smB[3 * 128 * 32];
  // XCD swizzle: flat id -> xcd*96+pos (768 = 8*96, bijective); groups 12 A-panels/XCD
  const int flat = (blockIdx.z * 32 + blockIdx.y) * 8 + blockIdx.x;
  const int nid = (flat & 7) * 96 + (flat >> 3);
  const int bx = nid & 7, by = (nid >> 3) & 31, z = nid >> 8;
  const u16* A = z == 0 ? xq : (z == 1 ? xk : xv);
  const u16* W = z == 0 ? Wq : (z == 1 ? Wk : Wv);
  const float* bias = z == 0 ? bq : (z == 1 ? bk : bv);
  u16* out = z == 0 ? Qh : (z == 1 ? Kh : Vt);
  const float sc = z == 0 ? QSCALE : 1.0f;
  const int gm0 = by * 128, gn0 = bx * 128;
  f32x4 acc[4][4] = {};
  gemm_core<4, 4>(A, W, smA, smB, acc, gm0, gn0);

  const int tid = threadIdx.x;
  const int w = tid >> 6, l = tid & 63, g = (l >> 4) & 3, r = l & 15;
  const int wm = w >> 1, wn = w & 1;
#pragma unroll
  for (int mt = 0; mt < 4; ++mt) {
#pragma unroll
    for (int nt = 0; nt < 4; ++nt) {
      int ncol = gn0 + wn * 64 + nt * 16 + r;
      int h = ncol >> 6, dk = ncol & 63;
      float bb = bias[ncol];
      int mrow0 = gm0 + wm * 64 + mt * 16 + g * 4;
      int b = mrow0 >> 11, s0 = mrow0 & 2047;
      if (z < 2) {
#pragma unroll
        for (int i = 0; i < 4; ++i)
          out[(((size_t)b * Hh + h) * Ss + s0 + i) * DKc + dk] =
              f2bf((acc[mt][nt][i] + bb) * sc);
      } else {
        ushort4 ov;
        ov.x = f2bf(acc[mt][nt][0] + bb);
        ov.y = f2bf(acc[mt][nt][1] + bb);
        ov.z = f2bf(acc[mt][nt][2] + bb);
        ov.w = f2bf(acc[mt][nt][3] + bb);
        *reinterpret_cast<ushort4*>(
            &out[(((size_t)b * Hh + h) * DKc + dk) * Ss + s0]) = ov;
      }
    }
  }
}

// ---------------- causal flash attention v5: 128 kv per barrier period ----------
// 4 K/V LDS slots (pair-double-buffer). Per iteration: two 64-kv subtiles A,B with
// ONE vmcnt+barrier, one max-tree/defer-check, QK^T(B) as independent MFMA work.
__global__ __launch_bounds__(256, 2) void attn(
    const u16* __restrict__ Qh, const u16* __restrict__ Kh,
    const u16* __restrict__ Vt, u16* __restrict__ Ob) {
  __shared__ u16 smK[4][64 * 64];
  __shared__ u16 smV[4][64 * 64];
  __shared__ u16 smP[4][16 * 72];

  // XCD-aware remap: XCD k (= fid%8) owns bh in [4k, 4k+4) -> 2MB KV set per L2
  const int fid = blockIdx.y * 16 + blockIdx.x;
  const int xcd = fid & 7, slot = fid >> 3;
  const int bh = xcd * 4 + (slot >> 4);
  const int pair = slot & 15;
  const int bidx = bh >> 4, h = bh & 15;

  const int tid = threadIdx.x, w = tid >> 6, l = tid & 63;
  const int g = (l >> 4) & 3, r = l & 15;

  const u16* Qb = Qh + (size_t)bh * Ss * DKc;
  const u16* Kb = Kh + (size_t)bh * Ss * DKc;
  const u16* Vb = Vt + (size_t)bh * DKc * Ss;
  u16* Pw = smP[w];

  const int srow0 = tid >> 3, schunk = tid & 7;

  auto stage = [&](int sl, int kb) {
#pragma unroll
    for (int j = 0; j < 2; ++j) {
      int row = j * 32 + srow0;
      int c = schunk ^ (row & 7);
      u16* dK = smK[sl] + (j * 256 + w * 64) * 8;
      u16* dV = smV[sl] + (j * 256 + w * 64) * 8;
      gload_lds16(Kb + (size_t)(kb + row) * DKc + c * 8, dK);
      gload_lds16(Vb + (size_t)row * Ss + kb + c * 8, dV);
    }
  };

  for (int t2 = 0; t2 < 2; ++t2) {
    const int qt = (t2 == 0) ? (31 - pair) : pair;
    const int ntile = qt + 1;
    const int npair = (ntile + 1) >> 1;
    const int qw = qt * 64 + w * 16;
    const int q = qw + r;                 // this lane's q row

    if (t2) __builtin_amdgcn_s_barrier();   // t2=0 readers done before re-stage

    short8 qf[2];
    qf[0] = *reinterpret_cast<const short8*>(Qb + (size_t)q * DKc + g * 8);
    qf[1] = *reinterpret_cast<const short8*>(Qb + (size_t)q * DKc + 32 + g * 8);

    stage(0, 0);
    if (ntile > 1) stage(1, 64);

    f32x4 o[4] = {};
    float m_s = -3e38f, l_s = 0.f;

    for (int pp = 0; pp < npair; ++pp) {
      const int slotA = (pp & 1) * 2;
      const int kbA = pp * 128;
      const bool hasB = (2 * pp + 1 < ntile);
      const bool diagA = (2 * pp == qt);
      const bool diagB = hasB && (2 * pp + 1 == qt);

      asm volatile("s_waitcnt vmcnt(0)" ::: "memory");
      __builtin_amdgcn_s_barrier();         // pair pp staged; pair pp-1 reads done
      __builtin_amdgcn_sched_barrier(0);
      if (pp + 1 < npair) {
        int nb = ((pp + 1) & 1) * 2;
        stage(nb, kbA + 128);
        if (2 * pp + 3 < ntile) stage(nb + 1, kbA + 192);
      }

      // QK^T swapped: sA/sB rows kv, cols q (log2-scaled via QSCALE)
      f32x4 sA[4] = {}, sB[4] = {};
      __builtin_amdgcn_s_setprio(1);
#pragma unroll
      for (int ks = 0; ks < 2; ++ks)
#pragma unroll
        for (int nt = 0; nt < 4; ++nt) {
          int row = nt * 16 + r;
          int ch = (ks * 4 + g) ^ (row & 7);
          short8 kf = *reinterpret_cast<const short8*>(&smK[slotA][row * 64 + ch * 8]);
          sA[nt] = mfma16(kf, qf[ks], sA[nt]);
        }
      if (hasB) {
#pragma unroll
        for (int ks = 0; ks < 2; ++ks)
#pragma unroll
          for (int nt = 0; nt < 4; ++nt) {
            int row = nt * 16 + r;
            int ch = (ks * 4 + g) ^ (row & 7);
            short8 kf = *reinterpret_cast<const short8*>(&smK[slotA + 1][row * 64 + ch * 8]);
            sB[nt] = mfma16(kf, qf[ks], sB[nt]);
          }
      }
      __builtin_amdgcn_s_setprio(0);

      const int qloc = w * 16 + r;
      if (diagA) {
#pragma unroll
        for (int nt = 0; nt < 4; ++nt)
#pragma unroll
          for (int i = 0; i < 4; ++i)
            if (nt * 16 + g * 4 + i > qloc) sA[nt][i] = -1e30f;
      }
      if (diagB) {
#pragma unroll
        for (int nt = 0; nt < 4; ++nt)
#pragma unroll
          for (int i = 0; i < 4; ++i)
            if (nt * 16 + g * 4 + i > qloc) sB[nt][i] = -1e30f;
      }

      // one max-tree + defer-check per 128 kv
      float mx0 = fmaxf(fmaxf(sA[0][0], sA[0][1]), fmaxf(sA[0][2], sA[0][3]));
      float mx1 = fmaxf(fmaxf(sA[1][0], sA[1][1]), fmaxf(sA[1][2], sA[1][3]));
      float mx2 = fmaxf(fmaxf(sA[2][0], sA[2][1]), fmaxf(sA[2][2], sA[2][3]));
      float mx3 = fmaxf(fmaxf(sA[3][0], sA[3][1]), fmaxf(sA[3][2], sA[3][3]));
      float mx = fmaxf(fmaxf(mx0, mx1), fmaxf(mx2, mx3));
      if (hasB) {
        float nx0 = fmaxf(fmaxf(sB[0][0], sB[0][1]), fmaxf(sB[0][2], sB[0][3]));
        float nx1 = fmaxf(fmaxf(sB[1][0], sB[1][1]), fmaxf(sB[1][2], sB[1][3]));
        float nx2 = fmaxf(fmaxf(sB[2][0], sB[2][1]), fmaxf(sB[2][2], sB[2][3]));
        float nx3 = fmaxf(fmaxf(sB[3][0], sB[3][1]), fmaxf(sB[3][2], sB[3][3]));
        mx = fmaxf(mx, fmaxf(fmaxf(nx0, nx1), fmaxf(nx2, nx3)));
      }

      if (__any(mx > m_s + 8.f)) {          // defer-max (log2 domain, THR=8)
        float mr = fmaxf(mx, __shfl_xor(mx, 16));
        mr = fmaxf(mr, __shfl_xor(mr, 32));
        float mn = fmaxf(m_s, mr);
        float f = __builtin_amdgcn_exp2f(m_s - mn);
        m_s = mn;
        l_s *= f;
#pragma unroll
        for (int dt = 0; dt < 4; ++dt) {
          o[dt][0] *= f; o[dt][1] *= f; o[dt][2] *= f; o[dt][3] *= f;
        }
      }

      // subtile A: P + l, then PV
#pragma unroll
      for (int nt = 0; nt < 4; ++nt) {
        float p0 = __builtin_amdgcn_exp2f(sA[nt][0] - m_s);
        float p1 = __builtin_amdgcn_exp2f(sA[nt][1] - m_s);
        float p2 = __builtin_amdgcn_exp2f(sA[nt][2] - m_s);
        float p3 = __builtin_amdgcn_exp2f(sA[nt][3] - m_s);
        l_s += (p0 + p1) + (p2 + p3);
        *reinterpret_cast<u32*>(&Pw[r * 72 + nt * 16 + g * 4])     = pk_bf16(p0, p1);
        *reinterpret_cast<u32*>(&Pw[r * 72 + nt * 16 + g * 4 + 2]) = pk_bf16(p2, p3);
      }
      __builtin_amdgcn_s_setprio(1);
#pragma unroll
      for (int ks = 0; ks < 2; ++ks) {
        short8 pf = *reinterpret_cast<const short8*>(&Pw[r * 72 + ks * 32 + g * 8]);
#pragma unroll
        for (int dt = 0; dt < 4; ++dt) {
          int row = dt * 16 + r;
          int ch = (ks * 4 + g) ^ (row & 7);
          short8 vf = *reinterpret_cast<const short8*>(&smV[slotA][row * 64 + ch * 8]);
          o[dt] = mfma16(vf, pf, o[dt]);
        }
      }
      __builtin_amdgcn_s_setprio(0);

      // subtile B
      if (hasB) {
#pragma unroll
        for (int nt = 0; nt < 4; ++nt) {
          float p0 = __builtin_amdgcn_exp2f(sB[nt][0] - m_s);
          float p1 = __builtin_amdgcn_exp2f(sB[nt][1] - m_s);
          float p2 = __builtin_amdgcn_exp2f(sB[nt][2] - m_s);
          float p3 = __builtin_amdgcn_exp2f(sB[nt][3] - m_s);
          l_s += (p0 + p1) + (p2 + p3);
          *reinterpret_cast<u32*>(&Pw[r * 72 + nt * 16 + g * 4])     = pk_bf16(p0, p1);
          *reinterpret_cast<u32*>(&Pw[r * 72 + nt * 16 + g * 4 + 2]) = pk_bf16(p2, p3);
        }
        __builtin_amdgcn_s_setprio(1);
#pragma unroll
        for (int ks = 0; ks < 2; ++ks) {
          short8 pf = *reinterpret_cast<const short8*>(&Pw[r * 72 + ks * 32 + g * 8]);
#pragma unroll
          for (int dt = 0; dt < 4; ++dt) {
            int row = dt * 16 + r;
            int ch = (ks * 4 + g) ^ (row & 7);
            short8 vf = *reinterpret_cast<const short8*>(&smV[slotA + 1][row * 64 + ch * 8]);
            o[dt] = mfma16(vf, pf, o[dt]);
          }
        }
        __builtin_amdgcn_s_setprio(0);
      }
    }

    // epilogue: lane (g,r) holds O^T[d = dt*16+g*4+i][q]; reduce partial l across g
    float lt = l_s;
    lt += __shfl_xor(lt, 16);
    lt += __shfl_xor(lt, 32);
    float inv = 1.f / lt;
    size_t ro = ((size_t)bidx * Ss + q) * Dd + h * DKc;
#pragma unroll
    for (int dt = 0; dt < 4; ++dt) {
      ushort4 ov;
      ov.x = f2bf(o[dt][0] * inv);
      ov.y = f2bf(o[dt][1] * inv);
      ov.z = f2bf(o[dt][2] * inv);
      ov.w = f2bf(o[dt][3] * inv);
      *reinterpret_cast<ushort4*>(&Ob[ro + dt * 16 + g * 4]) = ov;
    }
  }
}

// ---------------- output projection: 64x128 tiles (512 blocks), fp32 out + bias ----
__global__ __launch_bounds__(256, 2) void gemm_out(
    const u16* __restrict__ Ob, const u16* __restrict__ Wo,
    const float* __restrict__ bo, float* __restrict__ out) {
  __shared__ u16 smA[3 * 64 * 32], smB[3 * 128 * 32];
  const int flat = blockIdx.y * 8 + blockIdx.x;
  const int nid = (flat & 7) * 64 + (flat >> 3);
  const int bx = nid & 7, by = nid >> 3;
  const int gm0 = by * 64, gn0 = bx * 128;
  f32x4 acc[2][4] = {};
  gemm_core<2, 4>(Ob, Wo, smA, smB, acc, gm0, gn0);

  const int tid = threadIdx.x;
  const int w = tid >> 6, l = tid & 63, g = (l >> 4) & 3, r = l & 15;
  const int wm = w >> 1, wn = w & 1;
#pragma unroll
  for (int mt = 0; mt < 2; ++mt) {
#pragma unroll
    for (int nt = 0; nt < 4; ++nt) {
      int ncol = gn0 + wn * 64 + nt * 16 + r;
      float bb = bo[ncol];
#pragma unroll
      for (int i = 0; i < 4; ++i) {
        int mrow = gm0 + wm * 32 + mt * 16 + g * 4 + i;
        out[(size_t)mrow * Dd + ncol] = acc[mt][nt][i] + bb;
      }
    }
  }
}

extern "C" void kernel_launch(void* const* d_in, const int* in_sizes, int n_in,
                              void* d_out, int out_size, void* d_ws, size_t ws_size,
                              hipStream_t stream) {
  const float* q    = (const float*)d_in[0];
  const float* k    = (const float*)d_in[1];
  const float* v    = (const float*)d_in[2];
  // d_in[3] = mask (causal tril) — handled analytically
  const float* wq_w = (const float*)d_in[4];
  const float* wq_b = (const float*)d_in[5];
  const float* wk_w = (const float*)d_in[6];
  const float* wk_b = (const float*)d_in[7];
  const float* wv_w = (const float*)d_in[8];
  const float* wv_b = (const float*)d_in[9];
  const float* wo_w = (const float*)d_in[10];
  const float* wo_b = (const float*)d_in[11];

  char* ws = (char*)d_ws;
  u16* xq  = (u16*)(ws + 0);
  u16* xk  = (u16*)(ws + 8388608);
  u16* xv  = (u16*)(ws + 16777216);
  u16* Wqb = (u16*)(ws + 25165824);
  u16* Wkb = (u16*)(ws + 27262976);
  u16* Wvb = (u16*)(ws + 29360128);
  u16* Wob = (u16*)(ws + 31457280);
  u16* Qh  = (u16*)(ws + 33554432);
  u16* Kh  = (u16*)(ws + 41943040);
  u16* Vt  = (u16*)(ws + 50331648);
  u16* Ob  = (u16*)(ws + 0);        // alias xq: dead after projections

  CvtArgs ca;
  ca.in[0] = q;    ca.out[0] = xq;  ca.n[0] = 4194304;
  ca.in[1] = k;    ca.out[1] = xk;  ca.n[1] = 4194304;
  ca.in[2] = v;    ca.out[2] = xv;  ca.n[2] = 4194304;
  ca.in[3] = wq_w; ca.out[3] = Wqb; ca.n[3] = 1048576;
  ca.in[4] = wk_w; ca.out[4] = Wkb; ca.n[4] = 1048576;
  ca.in[5] = wv_w; ca.out[5] = Wvb; ca.n[5] = 1048576;
  ca.in[6] = wo_w; ca.out[6] = Wob; ca.n[6] = 1048576;

  cvt_all<<<dim3(4096, 1, 7), 256, 0, stream>>>(ca);
  proj_qkv<<<dim3(8, 32, 3), 256, 0, stream>>>(xq, xk, xv, Wqb, Wkb, Wvb,
                                               wq_b, wk_b, wv_b, Qh, Kh, Vt);
  attn<<<dim3(16, 32), 256, 0, stream>>>(Qh, Kh, Vt, Ob);
  gemm_out<<<dim3(8, 64), 256, 0, stream>>>(Ob, Wob, wo_b, (float*)d_out);
}